// Round 6
// baseline (822.330 us; speedup 1.0000x reference)
//
#include <hip/hip_runtime.h>
#include <hip/hip_bf16.h>

// GlobalAttention: Q_LEN=512, SRC_LEN=2048, B=32, D=1024, F=2048
// Round 6: templated-tile pipelined MFMA GEMM.
//  - 4-deep LDS pipeline, counted vmcnt, 1 barrier/iter, setprio, XCD swizzle
//    (round-5 skeleton, which raised MfmaUtil 29->37%)
//  - 16x16x32 fragments with round-2 slot-XOR swizzle (0 measured conflicts;
//    round-5's 32x32 frags caused 1.9e7 conflicts)
//  - tile shapes per GEMM so every dispatch fills >=256 blocks:
//      K1/K5: 256x256 (512t)   K2: 128x256 (512t)   K4: 128x128 (256t)
// Numerics identical to rounds 4/5 (absmax 0.0088).

typedef __attribute__((ext_vector_type(8))) short bf16x8;
typedef __attribute__((ext_vector_type(4))) float f32x4;

__device__ __forceinline__ ushort f2bf(float x) {
    unsigned u = __builtin_bit_cast(unsigned, x);
    u += 0x7FFFu + ((u >> 16) & 1u);
    return (ushort)(u >> 16);
}
__device__ __forceinline__ float bf2f(ushort h) {
    unsigned u = (unsigned)h << 16;
    return __builtin_bit_cast(float, u);
}
__device__ __forceinline__ void async16(const ushort* g, ushort* l) {
    __builtin_amdgcn_global_load_lds(
        (const __attribute__((address_space(1))) unsigned int*)g,
        (__attribute__((address_space(3))) unsigned int*)l, 16, 0, 0);
}

// ---------------------------------------------------------------------------
// gemmp: C[m,n] = sum_{seg} sum_k A_s[m*lda+k]*B_s[n*ldb+k]  (NT, K-segments)
// BMxBN tile, BK=32, THREADS (WRxWC waves, wave tile (BM/WR)x(BN/WC)),
// 16x16x32 MFMA frags (MI x NJ per wave).
// LDS: 4 pipeline buffers x (BM+BN)x32 bf16. Stage tile t+3 while computing t;
// per-iter counted vmcnt (2*LPT) -> barrier -> stage -> ds_read frags -> MFMA.
// Slot-XOR swizzle ((row>>1)&3) on stage source AND frag read (round-2 0-conflict).
// OUTMODE: 0=f32, 2=bf16 hi (+lo if non-null)(+bias if non-null), 3=tanh(x+bias)
// ---------------------------------------------------------------------------
template<int BM, int BN, int WR, int WC, int THREADS, int OUTMODE>
__global__ __launch_bounds__(THREADS, 2) void gemmp(
    const ushort* __restrict__ A0, const ushort* __restrict__ A1, const ushort* __restrict__ A2,
    const ushort* __restrict__ B0, const ushort* __restrict__ B1, const ushort* __restrict__ B2,
    long lda, long ldb, int tps, int nseg,
    const float* __restrict__ bias,
    float* __restrict__ Cf, ushort* __restrict__ Chi, ushort* __restrict__ Clo,
    long ldc, long sAb, long sBb, long sCb)
{
    constexpr int WTM = BM / WR, WTN = BN / WC;
    constexpr int MI = WTM / 16, NJ = WTN / 16;
    constexpr int CHA = BM * 4;                 // A 16B-chunks per tile
    constexpr int CHT = (BM + BN) * 4;          // total chunks
    constexpr int LPT = CHT / THREADS;          // loads per thread per STAGE
    constexpr int BUFE = (BM + BN) * 32;        // elements per buffer

    __shared__ ushort lds[4][BUFE];

    const int t   = threadIdx.x;
    const int l   = t & 63;
    const int wid = t >> 6;
    const int lr  = l & 15;
    const int lkp = ((l >> 4) ^ ((lr >> 1) & 3)) * 8;   // swizzled k-slot (elems)
    const int wm  = (wid / WC) * WTM;
    const int wn  = (wid % WC) * WTN;

    // XCD-aware bijective block swizzle (all grids here have nwg % 8 == 0)
    const int gx = gridDim.x, gy = gridDim.y;
    const int nwg = gx * gy * gridDim.z;
    int w = ((int)blockIdx.z * gy + (int)blockIdx.y) * gx + (int)blockIdx.x;
    w = (w & 7) * (nwg >> 3) + (w >> 3);
    const int bx = w % gx;
    const int by = (w / gx) % gy;
    const int bz = w / (gx * gy);

    const long m0 = (long)by * BM;
    const long n0 = (long)bx * BN;

    const ushort* Asg[3] = { A0 + (long)bz * sAb, A1 + (long)bz * sAb, A2 + (long)bz * sAb };
    const ushort* Bsg[3] = { B0 + (long)bz * sBb, B1 + (long)bz * sBb, B2 + (long)bz * sBb };
    const int NTt = nseg * tps;

    // staging: chunk c -> operand (c<CHA ? A : B), row cc>>2, stored slot cc&3;
    // global source slot = (cc&3) ^ ((row>>1)&3). LDS dest linear at c*8 elems.
    long goffs[LPT];
    bool isA[LPT];
#pragma unroll
    for (int i = 0; i < LPT; ++i) {
        int c = t + i * THREADS;
        bool a = (c < CHA);
        int cc = a ? c : (c - CHA);
        int row = cc >> 2;
        int slot = (cc & 3) ^ ((row >> 1) & 3);
        goffs[i] = ((a ? m0 : n0) + row) * (a ? lda : ldb) + slot * 8;
        isA[i] = a;
    }

    auto STAGE = [&](int kt, int buf) {
        int s2 = (kt >= tps) + (kt >= 2 * tps);
        long ko = (long)(kt - s2 * tps) * 32;
        const ushort* Ak = Asg[s2] + ko;
        const ushort* Bk = Bsg[s2] + ko;
        ushort* d = &lds[buf][0];
#pragma unroll
        for (int i = 0; i < LPT; ++i)
            async16((isA[i] ? Ak : Bk) + goffs[i], d + (t + i * THREADS) * 8);
    };

    const f32x4 zero = {0.f, 0.f, 0.f, 0.f};
    f32x4 acc[MI][NJ];
#pragma unroll
    for (int mb = 0; mb < MI; ++mb)
#pragma unroll
        for (int nb = 0; nb < NJ; ++nb) acc[mb][nb] = zero;

    const int aBase = (wm + lr) * 32 + lkp;
    const int bBase = BM * 32 + (wn + lr) * 32 + lkp;

    STAGE(0, 0);
    STAGE(1, 1);
    STAGE(2, 2);

    for (int kt = 0; kt < NTt; ++kt) {
        if (kt < NTt - 2) {
            if constexpr (LPT == 4) asm volatile("s_waitcnt vmcnt(8)" ::: "memory");
            else                    asm volatile("s_waitcnt vmcnt(6)" ::: "memory");
        } else if (kt == NTt - 2) {
            if constexpr (LPT == 4) asm volatile("s_waitcnt vmcnt(4)" ::: "memory");
            else                    asm volatile("s_waitcnt vmcnt(3)" ::: "memory");
        } else {
            asm volatile("s_waitcnt vmcnt(0)" ::: "memory");
        }
        __builtin_amdgcn_sched_barrier(0);
        __builtin_amdgcn_s_barrier();        // all waves' tile-kt loads landed;
        __builtin_amdgcn_sched_barrier(0);   // also closes iter kt-1's reads
        asm volatile("" ::: "memory");

        if (kt + 3 < NTt) STAGE(kt + 3, (kt + 3) & 3);   // overwrites buf[(kt-1)&3]

        const ushort* buf = &lds[kt & 3][0];
        bf16x8 ah[MI], bh[NJ];
#pragma unroll
        for (int mb = 0; mb < MI; ++mb)
            ah[mb] = *(const bf16x8*)(buf + aBase + mb * 512);
#pragma unroll
        for (int nb = 0; nb < NJ; ++nb)
            bh[nb] = *(const bf16x8*)(buf + bBase + nb * 512);
        __builtin_amdgcn_s_setprio(1);
#pragma unroll
        for (int mb = 0; mb < MI; ++mb)
#pragma unroll
            for (int nb = 0; nb < NJ; ++nb)
                acc[mb][nb] = __builtin_amdgcn_mfma_f32_16x16x32_bf16(
                    ah[mb], bh[nb], acc[mb][nb], 0, 0, 0);
        __builtin_amdgcn_s_setprio(0);
    }

    // epilogue: 16x16 C/D mapping col = l&15, row = (l>>4)*4 + reg
    float*  Cfb = Cf  ? (Cf  + (long)bz * sCb) : nullptr;
    ushort* Chb = Chi ? (Chi + (long)bz * sCb) : nullptr;
    ushort* Clb = Clo ? (Clo + (long)bz * sCb) : nullptr;
    const int mrow = (l >> 4) * 4;
#pragma unroll
    for (int nb = 0; nb < NJ; ++nb) {
        long n = n0 + wn + nb * 16 + lr;
        float bv = 0.f;
        if (OUTMODE == 3) bv = bias[n];
        if (OUTMODE == 2) { if (bias) bv = bias[n]; }
#pragma unroll
        for (int mb = 0; mb < MI; ++mb) {
            long mbase = m0 + wm + mb * 16 + mrow;
#pragma unroll
            for (int r = 0; r < 4; ++r) {
                float x = acc[mb][nb][r] + bv;
                long idx = (mbase + r) * ldc + n;
                if (OUTMODE == 3) {
                    Cfb[idx] = tanhf(x);
                } else if (OUTMODE == 2) {
                    ushort h = f2bf(x);
                    Chb[idx] = h;
                    if (Clb) Clb[idx] = f2bf(x - bf2f(h));
                } else {
                    Cfb[idx] = x;
                }
            }
        }
    }
}

// ---------------------------------------------------------------------------
// Elementwise f32 -> (hi, lo) bf16 pair
// ---------------------------------------------------------------------------
__global__ __launch_bounds__(256) void split_pair_k(
    const float* __restrict__ in, ushort* __restrict__ hi, ushort* __restrict__ lo, long n4)
{
    long i = (long)blockIdx.x * 256 + threadIdx.x;
    const long stride = (long)gridDim.x * 256;
    for (; i < n4; i += stride) {
        float4 x = ((const float4*)in)[i];
        ushort4 h, lw;
        h.x = f2bf(x.x); lw.x = f2bf(x.x - bf2f(h.x));
        h.y = f2bf(x.y); lw.y = f2bf(x.y - bf2f(h.y));
        h.z = f2bf(x.z); lw.z = f2bf(x.z - bf2f(h.z));
        h.w = f2bf(x.w); lw.w = f2bf(x.w - bf2f(h.w));
        ((ushort4*)hi)[i] = h;
        ((ushort4*)lo)[i] = lw;
    }
}

// ---------------------------------------------------------------------------
// values [2048][32][1024] f32 -> per batch-group:
//   vhi/vlo [(s*gc+bi)][1024] bf16 pair  (K2 B-operand, NT)
//   vT [bi][1024][2048] bf16             (K4 B-operand, NT)
// ---------------------------------------------------------------------------
__global__ __launch_bounds__(256) void values_conv_k(
    const float* __restrict__ values,
    ushort* __restrict__ vhi, ushort* __restrict__ vlo, ushort* __restrict__ vT,
    int b0, int gc)
{
    __shared__ float tile[64][65];
    const int t  = threadIdx.x;
    const int s0 = blockIdx.x * 64;
    const int v0 = blockIdx.y * 64;
    const int bi = blockIdx.z;
    const int b  = b0 + bi;
#pragma unroll
    for (int i = 0; i < 4; ++i) {
        int c = t + i * 256;
        int r = c >> 4;
        int qq = c & 15;
        float4 x = *(const float4*)(values + ((long)(s0 + r) * 32 + b) * 1024 + v0 + qq * 4);
        ushort4 h, lw;
        h.x = f2bf(x.x); lw.x = f2bf(x.x - bf2f(h.x));
        h.y = f2bf(x.y); lw.y = f2bf(x.y - bf2f(h.y));
        h.z = f2bf(x.z); lw.z = f2bf(x.z - bf2f(h.z));
        h.w = f2bf(x.w); lw.w = f2bf(x.w - bf2f(h.w));
        long rowoff = ((long)(s0 + r) * gc + bi) * 1024 + v0 + qq * 4;
        *(ushort4*)(vhi + rowoff) = h;
        *(ushort4*)(vlo + rowoff) = lw;
        tile[r][qq * 4 + 0] = x.x;
        tile[r][qq * 4 + 1] = x.y;
        tile[r][qq * 4 + 2] = x.z;
        tile[r][qq * 4 + 3] = x.w;
    }
    __syncthreads();
    const int vr = t >> 2;
    const int ss = (t & 3) * 16;
    ushort* dst = vT + ((long)bi * 1024 + v0 + vr) * 2048 + s0 + ss;
#pragma unroll
    for (int j = 0; j < 4; ++j) {
        ushort4 o;
        o.x = f2bf(tile[ss + j * 4 + 0][vr]);
        o.y = f2bf(tile[ss + j * 4 + 1][vr]);
        o.z = f2bf(tile[ss + j * 4 + 2][vr]);
        o.w = f2bf(tile[ss + j * 4 + 3][vr]);
        *(ushort4*)(dst + j * 4) = o;
    }
}

// softmax over 2048-rows, f32 in -> bf16 P out. One 256-thread block per row.
__global__ __launch_bounds__(256) void softmax2048b_k(
    const float* __restrict__ S, ushort* __restrict__ P)
{
    __shared__ float red[4];
    const long row = blockIdx.x;
    const float* p = S + row * 2048 + threadIdx.x * 8;
    float4 a = ((const float4*)p)[0];
    float4 b = ((const float4*)p)[1];

    float m = fmaxf(fmaxf(fmaxf(a.x, a.y), fmaxf(a.z, a.w)),
                    fmaxf(fmaxf(b.x, b.y), fmaxf(b.z, b.w)));
#pragma unroll
    for (int off = 32; off; off >>= 1) m = fmaxf(m, __shfl_xor(m, off));
    int wid = threadIdx.x >> 6;
    if ((threadIdx.x & 63) == 0) red[wid] = m;
    __syncthreads();
    m = fmaxf(fmaxf(red[0], red[1]), fmaxf(red[2], red[3]));
    __syncthreads();

    a.x = __expf(a.x - m); a.y = __expf(a.y - m);
    a.z = __expf(a.z - m); a.w = __expf(a.w - m);
    b.x = __expf(b.x - m); b.y = __expf(b.y - m);
    b.z = __expf(b.z - m); b.w = __expf(b.w - m);

    float s = a.x + a.y + a.z + a.w + b.x + b.y + b.z + b.w;
#pragma unroll
    for (int off = 32; off; off >>= 1) s += __shfl_xor(s, off);
    if ((threadIdx.x & 63) == 0) red[wid] = s;
    __syncthreads();
    s = red[0] + red[1] + red[2] + red[3];
    float inv = 1.0f / s;

    ushort* qp = P + row * 2048 + threadIdx.x * 8;
    ushort4 oA, oB;
    oA.x = f2bf(a.x * inv); oA.y = f2bf(a.y * inv);
    oA.z = f2bf(a.z * inv); oA.w = f2bf(a.w * inv);
    oB.x = f2bf(b.x * inv); oB.y = f2bf(b.y * inv);
    oB.z = f2bf(b.z * inv); oB.w = f2bf(b.w * inv);
    ((ushort4*)qp)[0] = oA;
    ((ushort4*)qp)[1] = oB;
}

// ===========================================================================
// Fallback fp32 path (used only if ws_size is too small)
// ===========================================================================
#define BMF 128
#define BNF 128
#define BKF 16

template<bool NT, int MODE>
__global__ __launch_bounds__(256) void gemm_f32(
    const float* __restrict__ A, const float* __restrict__ A2, int Ksplit,
    const float* __restrict__ Bm, const float* __restrict__ bias,
    float* __restrict__ C,
    long lda, long ldb, long ldc, int K,
    long sAb, long sBb, long sCb)
{
    __shared__ float As[BKF][BMF + 4];
    __shared__ float Bs[BKF][BNF + 4];

    const int bz = blockIdx.z;
    const float* Ab  = A + (long)bz * sAb;
    const float* A2b = A2 ? (A2 + (long)bz * sAb) : nullptr;
    const float* Bb  = Bm + (long)bz * sBb;
    float*       Cb  = C + (long)bz * sCb;

    const int m0 = blockIdx.y * BMF;
    const int n0 = blockIdx.x * BNF;
    const int t  = threadIdx.x;
    const int tx = t & 15;
    const int ty = t >> 4;

    float acc[8][8];
#pragma unroll
    for (int i = 0; i < 8; ++i)
#pragma unroll
        for (int j = 0; j < 8; ++j) acc[i][j] = 0.f;

    for (int k0 = 0; k0 < K; k0 += BKF) {
        const float* Asrc = (A2b && k0 >= Ksplit) ? (A2b - Ksplit) : Ab;
#pragma unroll
        for (int c = 0; c < 2; ++c) {
            int chunk = t + c * 256;
            int row = chunk >> 2;
            int kq  = chunk & 3;
            float4 v = *(const float4*)(Asrc + (long)(m0 + row) * lda + k0 + kq * 4);
            As[kq * 4 + 0][row] = v.x;
            As[kq * 4 + 1][row] = v.y;
            As[kq * 4 + 2][row] = v.z;
            As[kq * 4 + 3][row] = v.w;
        }
        if (NT) {
#pragma unroll
            for (int c = 0; c < 2; ++c) {
                int chunk = t + c * 256;
                int row = chunk >> 2;
                int kq  = chunk & 3;
                float4 v = *(const float4*)(Bb + (long)(n0 + row) * ldb + k0 + kq * 4);
                Bs[kq * 4 + 0][row] = v.x;
                Bs[kq * 4 + 1][row] = v.y;
                Bs[kq * 4 + 2][row] = v.z;
                Bs[kq * 4 + 3][row] = v.w;
            }
        } else {
#pragma unroll
            for (int c = 0; c < 2; ++c) {
                int chunk = t + c * 256;
                int kr = chunk >> 5;
                int vq = chunk & 31;
                float4 v = *(const float4*)(Bb + (long)(k0 + kr) * ldb + n0 + vq * 4);
                *(float4*)&Bs[kr][vq * 4] = v;
            }
        }
        __syncthreads();

#pragma unroll
        for (int k = 0; k < BKF; ++k) {
            float4 a0 = *(const float4*)&As[k][ty * 8];
            float4 a1 = *(const float4*)&As[k][ty * 8 + 4];
            float4 b0 = *(const float4*)&Bs[k][tx * 8];
            float4 b1 = *(const float4*)&Bs[k][tx * 8 + 4];
            float ar[8] = {a0.x, a0.y, a0.z, a0.w, a1.x, a1.y, a1.z, a1.w};
            float br[8] = {b0.x, b0.y, b0.z, b0.w, b1.x, b1.y, b1.z, b1.w};
#pragma unroll
            for (int i = 0; i < 8; ++i)
#pragma unroll
                for (int j = 0; j < 8; ++j)
                    acc[i][j] += ar[i] * br[j];
        }
        __syncthreads();
    }

    float brow[8];
    if (MODE >= 1) {
#pragma unroll
        for (int j = 0; j < 8; ++j) brow[j] = bias[n0 + tx * 8 + j];
    }
#pragma unroll
    for (int i = 0; i < 8; ++i) {
        long row = m0 + ty * 8 + i;
        float v[8];
#pragma unroll
        for (int j = 0; j < 8; ++j) {
            float x = acc[i][j];
            if (MODE >= 1) x += brow[j];
            if (MODE == 2) x = tanhf(x);
            v[j] = x;
        }
        float4* dst = (float4*)&Cb[row * ldc + n0 + tx * 8];
        dst[0] = make_float4(v[0], v[1], v[2], v[3]);
        dst[1] = make_float4(v[4], v[5], v[6], v[7]);
    }
}

__global__ __launch_bounds__(256) void softmax2048(float* __restrict__ S)
{
    __shared__ float red[4];
    float* p = S + (long)blockIdx.x * 2048 + threadIdx.x * 8;
    float4 a = ((float4*)p)[0];
    float4 b = ((float4*)p)[1];

    float m = fmaxf(fmaxf(fmaxf(a.x, a.y), fmaxf(a.z, a.w)),
                    fmaxf(fmaxf(b.x, b.y), fmaxf(b.z, b.w)));
#pragma unroll
    for (int off = 32; off; off >>= 1) m = fmaxf(m, __shfl_xor(m, off));
    int wid = threadIdx.x >> 6;
    if ((threadIdx.x & 63) == 0) red[wid] = m;
    __syncthreads();
    m = fmaxf(fmaxf(red[0], red[1]), fmaxf(red[2], red[3]));
    __syncthreads();

    a.x = __expf(a.x - m); a.y = __expf(a.y - m);
    a.z = __expf(a.z - m); a.w = __expf(a.w - m);
    b.x = __expf(b.x - m); b.y = __expf(b.y - m);
    b.z = __expf(b.z - m); b.w = __expf(b.w - m);

    float s = a.x + a.y + a.z + a.w + b.x + b.y + b.z + b.w;
#pragma unroll
    for (int off = 32; off; off >>= 1) s += __shfl_xor(s, off);
    if ((threadIdx.x & 63) == 0) red[wid] = s;
    __syncthreads();
    s = red[0] + red[1] + red[2] + red[3];
    float inv = 1.0f / s;

    a.x *= inv; a.y *= inv; a.z *= inv; a.w *= inv;
    b.x *= inv; b.y *= inv; b.z *= inv; b.w *= inv;
    ((float4*)p)[0] = a;
    ((float4*)p)[1] = b;
}

// ===========================================================================
extern "C" void kernel_launch(void* const* d_in, const int* in_sizes, int n_in,
                              void* d_out, int out_size, void* d_ws, size_t ws_size,
                              hipStream_t stream)
{
    const float* query  = (const float*)d_in[0];
    const float* values = (const float*)d_in[1];
    const float* W1     = (const float*)d_in[2];
    const float* b1     = (const float*)d_in[3];
    const float* W2     = (const float*)d_in[4];
    const float* b2     = (const float*)d_in[5];
    float* out = (float*)d_out;

    const int Bc = 32, QL = 512, SL = 2048, D = 1024, F = 2048;
    const long R = (long)QL * Bc;   // 16384

    char* p = (char*)d_ws;
    auto take = [&](size_t bytes) -> char* {
        char* r = p;
        p += (bytes + 255) & ~(size_t)255;
        return r;
    };

    ushort* q_hi  = (ushort*)take((size_t)R * D * 2);
    ushort* q_lo  = (ushort*)take((size_t)R * D * 2);
    ushort* w1_hi = (ushort*)take((size_t)D * D * 2);
    ushort* w1_lo = (ushort*)take((size_t)D * D * 2);
    ushort* w2_hi = (ushort*)take((size_t)D * F * 2);
    ushort* w2_lo = (ushort*)take((size_t)D * F * 2);
    ushort* qr_hi = (ushort*)take((size_t)R * D * 2);
    ushort* qr_lo = (ushort*)take((size_t)R * D * 2);
    ushort* at_hi = (ushort*)take((size_t)R * D * 2);
    size_t fixedBytes = (size_t)(p - (char*)d_ws);

    // per batch: vals hi+lo+vT (3 x 4 MB) + scores f32 (4 MB) + P bf16 (2 MB)
    const size_t perBatch = (size_t)SL * D * 2 * 3 + (size_t)QL * SL * 4 + (size_t)QL * SL * 2 + 2048;
    long availB = (long)ws_size - (long)fixedBytes;
    int g = availB > 0 ? (int)(availB / (long)perBatch) : 0;
    if (g > 32) g = 32;

    if (g >= 1) {
        // ----------------------- fast split-bf16 MFMA path -----------------
        ushort* vals_hi = (ushort*)take((size_t)SL * D * 2 * g);
        ushort* vals_lo = (ushort*)take((size_t)SL * D * 2 * g);
        ushort* vT      = (ushort*)take((size_t)SL * D * 2 * g);
        float*  scores  = (float*) take((size_t)QL * SL * 4 * g);
        ushort* P       = (ushort*)take((size_t)QL * SL * 2 * g);

        split_pair_k<<<2048, 256, 0, stream>>>(query, q_hi, q_lo, R * D / 4);
        split_pair_k<<<1024, 256, 0, stream>>>(W1, w1_hi, w1_lo, (long)D * D / 4);
        split_pair_k<<<1024, 256, 0, stream>>>(W2, w2_hi, w2_lo, (long)D * F / 4);

        // K1: qr = query.W1^T + b1  (3-term split segments) -> bf16 pair
        // grid 4 x 64 = 256 blocks
        gemmp<256, 256, 2, 4, 512, 2><<<dim3(D / 256, R / 256, 1), 512, 0, stream>>>(
            q_hi, q_hi, q_lo, w1_hi, w1_lo, w1_hi,
            D, D, 32, 3, b1,
            nullptr, qr_hi, qr_lo,
            D, 0, 0, 0);

        for (int b0 = 0; b0 < Bc; b0 += g) {
            int gc = (Bc - b0 < g) ? (Bc - b0) : g;

            values_conv_k<<<dim3(SL / 64, D / 64, gc), 256, 0, stream>>>(
                values, vals_hi, vals_lo, vT, b0, gc);

            // K2: scores = qr . values  (3-term split segments) -> f32
            // grid 8 x 4 x gc = 256 blocks at gc=8
            gemmp<128, 256, 2, 4, 512, 0><<<dim3(SL / 256, QL / 128, gc), 512, 0, stream>>>(
                qr_hi + (size_t)b0 * D, qr_hi + (size_t)b0 * D, qr_lo + (size_t)b0 * D,
                vals_hi, vals_lo, vals_hi,
                (long)Bc * D, (long)gc * D, 32, 3, nullptr,
                scores, nullptr, nullptr,
                SL, D, D, (long)QL * SL);

            softmax2048b_k<<<gc * QL, 256, 0, stream>>>(scores, P);

            // K4: att = P . vT  (1-term) -> bf16 hi only
            // grid 8 x 4 x gc = 256 blocks at gc=8, 2 blocks/CU
            gemmp<128, 128, 2, 2, 256, 2><<<dim3(D / 128, QL / 128, gc), 256, 0, stream>>>(
                P, P, P, vT, vT, vT,
                SL, SL, 64, 1, nullptr,
                nullptr, at_hi + (size_t)b0 * D, nullptr,
                (long)Bc * D, (long)QL * SL, (long)D * SL, D);
        }

        // K5: out = tanh([att | query] . W2^T + b2)  (1-term, 2 K-segments)
        // grid 4 x 64 = 256 blocks
        gemmp<256, 256, 2, 4, 512, 3><<<dim3(D / 256, R / 256, 1), 512, 0, stream>>>(
            at_hi, q_hi, q_hi, w2_hi, w2_hi + 1024, w2_hi,
            D, F, 32, 2, b2,
            out, nullptr, nullptr,
            D, 0, 0, 0);
        return;
    }

    // ----------------------- fp32 fallback ---------------------------------
    float* qr = (float*)d_ws;
    size_t qrBytes = (size_t)R * D * sizeof(float);
    float* sc = (float*)((char*)d_ws + qrBytes);
    size_t scPerB = (size_t)QL * SL * sizeof(float);

    int grp = 32;
    if (ws_size < qrBytes + 32 * scPerB) {
        size_t avail = ws_size > qrBytes ? ws_size - qrBytes : 0;
        grp = (int)(avail / scPerB);
        if (grp < 1)  grp = 1;
        if (grp > 32) grp = 32;
    }

    {
        dim3 gd(D / BNF, R / BMF, 1);
        gemm_f32<true, 1><<<gd, 256, 0, stream>>>(
            query, nullptr, 1 << 30, W1, b1, qr,
            D, D, D, D, 0, 0, 0);
    }
    for (int b0 = 0; b0 < Bc; b0 += grp) {
        int gg = (Bc - b0 < grp) ? (Bc - b0) : grp;
        {
            dim3 gd(SL / BNF, QL / BMF, gg);
            gemm_f32<true, 0><<<gd, 256, 0, stream>>>(
                qr + (size_t)b0 * D, nullptr, 1 << 30,
                values + (size_t)b0 * D, nullptr, sc,
                (long)Bc * D, (long)Bc * D, SL, D,
                D, D, (long)QL * SL);
        }
        softmax2048<<<gg * QL, 256, 0, stream>>>(sc);
        {
            dim3 gd(D / BNF, QL / BMF, gg);
            gemm_f32<false, 0><<<gd, 256, 0, stream>>>(
                sc, nullptr, 1 << 30,
                values + (size_t)b0 * D, nullptr, qr + (size_t)b0 * D,
                SL, (long)Bc * D, (long)Bc * D, SL,
                (long)QL * SL, D, D);
        }
    }
    {
        dim3 gd(D / BNF, R / BMF, 1);
        gemm_f32<true, 2><<<gd, 256, 0, stream>>>(
            qr, query, D, W2, b2, out,
            D, 2048, D, 2048, 0, 0, 0);
    }
}

// Round 7
// 641.450 us; speedup vs baseline: 1.2820x; 1.2820x over previous
//
#include <hip/hip_runtime.h>
#include <hip/hip_bf16.h>

// GlobalAttention: Q_LEN=512, SRC_LEN=2048, B=32, D=1024, F=2048
// Round 7: 8-phase-schedule 256x256 / BK=64 GEMM (catalog T2+T3+T4+T5):
//  - 2-buffer LDS (2 x 64KB), per K-tile 4 quadrant-phases, each phase:
//    [vmcnt(4)] -> s_barrier -> stage one half-tile of next K-tile ->
//    ds_read quadrant operands -> setprio(1) 16 MFMA setprio(0)
//  - counted vmcnt never drains to 0 in steady state (stage order A0,B0,B1,A1
//    vs read order A0B0/B1/A1/B0 makes vmcnt(4) exact at phases 0-2)
//  - 8-slot XOR swizzle c16^(row&7) on BOTH stage source and ds_read
//  - wave->quadrant mapping such that quadrant q reads exactly halves (Aq,Bq)
// Numerics identical to rounds 4-6 (absmax 0.0088).

typedef __attribute__((ext_vector_type(8))) short bf16x8;
typedef __attribute__((ext_vector_type(4))) float f32x4;

__device__ __forceinline__ ushort f2bf(float x) {
    unsigned u = __builtin_bit_cast(unsigned, x);
    u += 0x7FFFu + ((u >> 16) & 1u);
    return (ushort)(u >> 16);
}
__device__ __forceinline__ float bf2f(ushort h) {
    unsigned u = (unsigned)h << 16;
    return __builtin_bit_cast(float, u);
}
__device__ __forceinline__ void async16(const ushort* g, ushort* l) {
    __builtin_amdgcn_global_load_lds(
        (const __attribute__((address_space(1))) unsigned int*)g,
        (__attribute__((address_space(3))) unsigned int*)l, 16, 0, 0);
}

#define WAITVM(N) asm volatile("s_waitcnt vmcnt(" #N ")" ::: "memory")
#define BAR() do { __builtin_amdgcn_sched_barrier(0); \
                   __builtin_amdgcn_s_barrier();      \
                   __builtin_amdgcn_sched_barrier(0); } while (0)

// read A-quadrant QM (4 m-frags x 2 k-windows) into av
#define RD_A(QM)                                                              \
  _Pragma("unroll") for (int mi = 0; mi < 4; ++mi)                            \
  _Pragma("unroll") for (int w = 0; w < 2; ++w) {                             \
    const int row_ = (QM)*128 + wmg*64 + mi*16 + lr;                          \
    av[mi][w] = *(const bf16x8*)(bufc + row_*64 + (((w*4+lg)^(lr&7))*8));     \
  }
// read B-quadrant QN (2 n-frags x 2 k-windows) into bv
#define RD_B(QN)                                                              \
  _Pragma("unroll") for (int nj = 0; nj < 2; ++nj)                            \
  _Pragma("unroll") for (int w = 0; w < 2; ++w) {                             \
    const int row_ = (QN)*128 + wnd*32 + nj*16 + lr;                          \
    bv[nj][w] = *(const bf16x8*)(bufc + 16384 + row_*64 + (((w*4+lg)^(lr&7))*8)); \
  }
#define MM(QM,QN)                                                             \
  __builtin_amdgcn_s_setprio(1);                                              \
  _Pragma("unroll") for (int w = 0; w < 2; ++w)                               \
  _Pragma("unroll") for (int mi = 0; mi < 4; ++mi)                            \
  _Pragma("unroll") for (int nj = 0; nj < 2; ++nj)                            \
    acc[(QM)*4+mi][(QN)*2+nj] = __builtin_amdgcn_mfma_f32_16x16x32_bf16(      \
        av[mi][w], bv[nj][w], acc[(QM)*4+mi][(QN)*2+nj], 0, 0, 0);            \
  __builtin_amdgcn_s_setprio(0);

// ---------------------------------------------------------------------------
// gemm8p: C[m,n] = sum_{seg} sum_k A_s[m*lda+k]*B_s[n*ldb+k]  (NT, K-segments)
// 256x256 tile, BK=64, 512 thr (8 waves: wmg=wid>>2 in {0,1}, wnd=wid&3).
// Wave sub-tile: rows {wmg*64..+63} u {+128..}, cols {wnd*32..+31} u {+128..}
// (quadrant (qm,qn) adds qm*128 / qn*128) -> quadrant q touches exactly
// half-tiles A_qm, B_qn. acc[8][4] f32x4 frags of 16x16x32.
// LDS buffer (per K-tile): A [256][64] at 0, B [256][64] at 16384 elems;
// halves of 128 rows; 8-slot XOR swizzle c16^(row&7) both sides.
// OUTMODE: 0=f32, 2=bf16 hi (+lo if non-null)(+bias if non-null), 3=tanh(x+bias)
// ---------------------------------------------------------------------------
template<int OUTMODE>
__global__ __launch_bounds__(512, 2) void gemm8p(
    const ushort* __restrict__ A0s, const ushort* __restrict__ A1s, const ushort* __restrict__ A2s,
    const ushort* __restrict__ B0s, const ushort* __restrict__ B1s, const ushort* __restrict__ B2s,
    long lda, long ldb, int tps, int nseg,
    const float* __restrict__ bias,
    float* __restrict__ Cf, ushort* __restrict__ Chi, ushort* __restrict__ Clo,
    long ldc, long sAb, long sBb, long sCb)
{
    __shared__ ushort lds[2][32768];   // 2 x 64 KiB

    const int t   = threadIdx.x;
    const int l   = t & 63;
    const int wid = t >> 6;
    const int lr  = l & 15;
    const int lg  = l >> 4;
    const int wmg = wid >> 2;   // 0..1  (m position)
    const int wnd = wid & 3;    // 0..3  (n position)

    // XCD-aware bijective block swizzle (all grids have nwg % 8 == 0);
    // z-major linearization so each XCD chunk covers whole batches.
    const int gx = gridDim.x, gy = gridDim.y;
    const int nwg = gx * gy * gridDim.z;
    int w0 = ((int)blockIdx.z * gy + (int)blockIdx.y) * gx + (int)blockIdx.x;
    w0 = (w0 & 7) * (nwg >> 3) + (w0 >> 3);
    const int bx = w0 % gx;
    const int by = (w0 / gx) % gy;
    const int bz = w0 / (gx * gy);

    const long m0 = (long)by * 256;
    const long n0 = (long)bx * 256;

    const ushort* Asg[3] = { A0s + (long)bz * sAb, A1s + (long)bz * sAb, A2s + (long)bz * sAb };
    const ushort* Bsg[3] = { B0s + (long)bz * sBb, B1s + (long)bz * sBb, B2s + (long)bz * sBb };
    const int NTt = nseg * tps;

    // staging geometry: half-tile = 128 rows x 64 k (16 KB) = 2 loads/thread.
    // linear dest chunk (j*512+t): row=(chunk>>3), slot=t&7; source slot
    // pre-swizzled = (t&7)^(row&7)  (row+64 keeps &7 -> same cS for j=1).
    const int  rA = t >> 3;
    const long cS = (long)((t & 7) ^ (rA & 7)) * 8;

    auto STAGE = [&](int kt1, bool isB, int half, int destoff) {
        int s2 = (kt1 >= tps) + (kt1 >= 2 * tps);
        long ko = (long)(kt1 - s2 * tps) * 64;
        const ushort* base = isB ? Bsg[s2] : Asg[s2];
        long ld = isB ? ldb : lda;
        long rb = isB ? n0 : m0;
        const ushort* src = base + (rb + half * 128 + rA) * ld + ko + cS;
        ushort* d = &lds[kt1 & 1][destoff + t * 8];
        async16(src, d);
        async16(src + 64 * ld, d + 4096);
    };

    const f32x4 zero = {0.f, 0.f, 0.f, 0.f};
    f32x4 acc[8][4];
#pragma unroll
    for (int i = 0; i < 8; ++i)
#pragma unroll
        for (int j = 0; j < 4; ++j) acc[i][j] = zero;

    // prologue: tile 0 -> buf0, in per-tile stage order A0,B0,B1,A1
    STAGE(0, false, 0, 0);
    STAGE(0, true,  0, 16384);
    STAGE(0, true,  1, 24576);
    STAGE(0, false, 1, 8192);

    bf16x8 av[4][2], bv[2][2];

    for (int kt = 0; kt < NTt - 1; ++kt) {
        const ushort* bufc = &lds[kt & 1][0];
        // ph0: quadrant (0,0) reads A0,B0 (oldest 4 of this tile's 8 loads)
        WAITVM(4); BAR();
        STAGE(kt + 1, false, 0, 0);          // next A0
        RD_A(0); RD_B(0); MM(0, 0);
        // ph1: quadrant (0,1) reads B1 (loads 5-6); A held
        WAITVM(4); BAR();
        STAGE(kt + 1, true, 0, 16384);       // next B0
        RD_B(1); MM(0, 1);
        // ph2: quadrant (1,1) reads A1 (loads 7-8); B held
        WAITVM(4); BAR();
        STAGE(kt + 1, true, 1, 24576);       // next B1
        RD_A(1); MM(1, 1);
        // ph3: quadrant (1,0) re-reads B0 (already resident); A held
        BAR();
        STAGE(kt + 1, false, 1, 8192);       // next A1
        RD_B(0); MM(1, 0);
    }
    {   // last tile: no staging; tighter waits
        const ushort* bufc = &lds[(NTt - 1) & 1][0];
        WAITVM(4); BAR(); RD_A(0); RD_B(0); MM(0, 0);
        WAITVM(2); BAR(); RD_B(1); MM(0, 1);
        WAITVM(0); BAR(); RD_A(1); MM(1, 1);
        BAR();            RD_B(0); MM(1, 0);
    }

    // epilogue: 16x16 C/D mapping col = l&15, row = (l>>4)*4 + reg
    float*  Cfb = Cf  ? (Cf  + (long)bz * sCb) : nullptr;
    ushort* Chb = Chi ? (Chi + (long)bz * sCb) : nullptr;
    ushort* Clb = Clo ? (Clo + (long)bz * sCb) : nullptr;
#pragma unroll
    for (int qn = 0; qn < 2; ++qn)
#pragma unroll
    for (int nj = 0; nj < 2; ++nj) {
        long n = n0 + qn * 128 + wnd * 32 + nj * 16 + lr;
        float bvs = 0.f;
        if (OUTMODE == 3) bvs = bias[n];
        if (OUTMODE == 2) { if (bias) bvs = bias[n]; }
#pragma unroll
        for (int qm = 0; qm < 2; ++qm)
#pragma unroll
        for (int mi = 0; mi < 4; ++mi) {
            long mb = m0 + qm * 128 + wmg * 64 + mi * 16 + lg * 4;
#pragma unroll
            for (int r = 0; r < 4; ++r) {
                float x = acc[qm * 4 + mi][qn * 2 + nj][r] + bvs;
                long idx = (mb + r) * ldc + n;
                if (OUTMODE == 3) {
                    Cfb[idx] = tanhf(x);
                } else if (OUTMODE == 2) {
                    ushort h = f2bf(x);
                    Chb[idx] = h;
                    if (Clb) Clb[idx] = f2bf(x - bf2f(h));
                } else {
                    Cfb[idx] = x;
                }
            }
        }
    }
}

// ---------------------------------------------------------------------------
// Elementwise f32 -> (hi, lo) bf16 pair
// ---------------------------------------------------------------------------
__global__ __launch_bounds__(256) void split_pair_k(
    const float* __restrict__ in, ushort* __restrict__ hi, ushort* __restrict__ lo, long n4)
{
    long i = (long)blockIdx.x * 256 + threadIdx.x;
    const long stride = (long)gridDim.x * 256;
    for (; i < n4; i += stride) {
        float4 x = ((const float4*)in)[i];
        ushort4 h, lw;
        h.x = f2bf(x.x); lw.x = f2bf(x.x - bf2f(h.x));
        h.y = f2bf(x.y); lw.y = f2bf(x.y - bf2f(h.y));
        h.z = f2bf(x.z); lw.z = f2bf(x.z - bf2f(h.z));
        h.w = f2bf(x.w); lw.w = f2bf(x.w - bf2f(h.w));
        ((ushort4*)hi)[i] = h;
        ((ushort4*)lo)[i] = lw;
    }
}

// ---------------------------------------------------------------------------
// values [2048][32][1024] f32 -> per batch-group:
//   vhi/vlo [(s*gc+bi)][1024] bf16 pair  (K2 B-operand, NT)
//   vT [bi][1024][2048] bf16             (K4 B-operand, NT)
// ---------------------------------------------------------------------------
__global__ __launch_bounds__(256) void values_conv_k(
    const float* __restrict__ values,
    ushort* __restrict__ vhi, ushort* __restrict__ vlo, ushort* __restrict__ vT,
    int b0, int gc)
{
    __shared__ float tile[64][65];
    const int t  = threadIdx.x;
    const int s0 = blockIdx.x * 64;
    const int v0 = blockIdx.y * 64;
    const int bi = blockIdx.z;
    const int b  = b0 + bi;
#pragma unroll
    for (int i = 0; i < 4; ++i) {
        int c = t + i * 256;
        int r = c >> 4;
        int qq = c & 15;
        float4 x = *(const float4*)(values + ((long)(s0 + r) * 32 + b) * 1024 + v0 + qq * 4);
        ushort4 h, lw;
        h.x = f2bf(x.x); lw.x = f2bf(x.x - bf2f(h.x));
        h.y = f2bf(x.y); lw.y = f2bf(x.y - bf2f(h.y));
        h.z = f2bf(x.z); lw.z = f2bf(x.z - bf2f(h.z));
        h.w = f2bf(x.w); lw.w = f2bf(x.w - bf2f(h.w));
        long rowoff = ((long)(s0 + r) * gc + bi) * 1024 + v0 + qq * 4;
        *(ushort4*)(vhi + rowoff) = h;
        *(ushort4*)(vlo + rowoff) = lw;
        tile[r][qq * 4 + 0] = x.x;
        tile[r][qq * 4 + 1] = x.y;
        tile[r][qq * 4 + 2] = x.z;
        tile[r][qq * 4 + 3] = x.w;
    }
    __syncthreads();
    const int vr = t >> 2;
    const int ss = (t & 3) * 16;
    ushort* dst = vT + ((long)bi * 1024 + v0 + vr) * 2048 + s0 + ss;
#pragma unroll
    for (int j = 0; j < 4; ++j) {
        ushort4 o;
        o.x = f2bf(tile[ss + j * 4 + 0][vr]);
        o.y = f2bf(tile[ss + j * 4 + 1][vr]);
        o.z = f2bf(tile[ss + j * 4 + 2][vr]);
        o.w = f2bf(tile[ss + j * 4 + 3][vr]);
        *(ushort4*)(dst + j * 4) = o;
    }
}

// softmax over 2048-rows, f32 in -> bf16 P out. One 256-thread block per row.
__global__ __launch_bounds__(256) void softmax2048b_k(
    const float* __restrict__ S, ushort* __restrict__ P)
{
    __shared__ float red[4];
    const long row = blockIdx.x;
    const float* p = S + row * 2048 + threadIdx.x * 8;
    float4 a = ((const float4*)p)[0];
    float4 b = ((const float4*)p)[1];

    float m = fmaxf(fmaxf(fmaxf(a.x, a.y), fmaxf(a.z, a.w)),
                    fmaxf(fmaxf(b.x, b.y), fmaxf(b.z, b.w)));
#pragma unroll
    for (int off = 32; off; off >>= 1) m = fmaxf(m, __shfl_xor(m, off));
    int wid = threadIdx.x >> 6;
    if ((threadIdx.x & 63) == 0) red[wid] = m;
    __syncthreads();
    m = fmaxf(fmaxf(red[0], red[1]), fmaxf(red[2], red[3]));
    __syncthreads();

    a.x = __expf(a.x - m); a.y = __expf(a.y - m);
    a.z = __expf(a.z - m); a.w = __expf(a.w - m);
    b.x = __expf(b.x - m); b.y = __expf(b.y - m);
    b.z = __expf(b.z - m); b.w = __expf(b.w - m);

    float s = a.x + a.y + a.z + a.w + b.x + b.y + b.z + b.w;
#pragma unroll
    for (int off = 32; off; off >>= 1) s += __shfl_xor(s, off);
    if ((threadIdx.x & 63) == 0) red[wid] = s;
    __syncthreads();
    s = red[0] + red[1] + red[2] + red[3];
    float inv = 1.0f / s;

    ushort* qp = P + row * 2048 + threadIdx.x * 8;
    ushort4 oA, oB;
    oA.x = f2bf(a.x * inv); oA.y = f2bf(a.y * inv);
    oA.z = f2bf(a.z * inv); oA.w = f2bf(a.w * inv);
    oB.x = f2bf(b.x * inv); oB.y = f2bf(b.y * inv);
    oB.z = f2bf(b.z * inv); oB.w = f2bf(b.w * inv);
    ((ushort4*)qp)[0] = oA;
    ((ushort4*)qp)[1] = oB;
}

// ===========================================================================
// Fallback fp32 path (used only if ws_size is too small)
// ===========================================================================
#define BMF 128
#define BNF 128
#define BKF 16

template<bool NT, int MODE>
__global__ __launch_bounds__(256) void gemm_f32(
    const float* __restrict__ A, const float* __restrict__ A2, int Ksplit,
    const float* __restrict__ Bm, const float* __restrict__ bias,
    float* __restrict__ C,
    long lda, long ldb, long ldc, int K,
    long sAb, long sBb, long sCb)
{
    __shared__ float As[BKF][BMF + 4];
    __shared__ float Bs[BKF][BNF + 4];

    const int bz = blockIdx.z;
    const float* Ab  = A + (long)bz * sAb;
    const float* A2b = A2 ? (A2 + (long)bz * sAb) : nullptr;
    const float* Bb  = Bm + (long)bz * sBb;
    float*       Cb  = C + (long)bz * sCb;

    const int m0 = blockIdx.y * BMF;
    const int n0 = blockIdx.x * BNF;
    const int t  = threadIdx.x;
    const int tx = t & 15;
    const int ty = t >> 4;

    float acc[8][8];
#pragma unroll
    for (int i = 0; i < 8; ++i)
#pragma unroll
        for (int j = 0; j < 8; ++j) acc[i][j] = 0.f;

    for (int k0 = 0; k0 < K; k0 += BKF) {
        const float* Asrc = (A2b && k0 >= Ksplit) ? (A2b - Ksplit) : Ab;
#pragma unroll
        for (int c = 0; c < 2; ++c) {
            int chunk = t + c * 256;
            int row = chunk >> 2;
            int kq  = chunk & 3;
            float4 v = *(const float4*)(Asrc + (long)(m0 + row) * lda + k0 + kq * 4);
            As[kq * 4 + 0][row] = v.x;
            As[kq * 4 + 1][row] = v.y;
            As[kq * 4 + 2][row] = v.z;
            As[kq * 4 + 3][row] = v.w;
        }
        if (NT) {
#pragma unroll
            for (int c = 0; c < 2; ++c) {
                int chunk = t + c * 256;
                int row = chunk >> 2;
                int kq  = chunk & 3;
                float4 v = *(const float4*)(Bb + (long)(n0 + row) * ldb + k0 + kq * 4);
                Bs[kq * 4 + 0][row] = v.x;
                Bs[kq * 4 + 1][row] = v.y;
                Bs[kq * 4 + 2][row] = v.z;
                Bs[kq * 4 + 3][row] = v.w;
            }
        } else {
#pragma unroll
            for (int c = 0; c < 2; ++c) {
                int chunk = t + c * 256;
                int kr = chunk >> 5;
                int vq = chunk & 31;
                float4 v = *(const float4*)(Bb + (long)(k0 + kr) * ldb + n0 + vq * 4);
                *(float4*)&Bs[kr][vq * 4] = v;
            }
        }
        __syncthreads();

#pragma unroll
        for (int k = 0; k < BKF; ++k) {
            float4 a0 = *(const float4*)&As[k][ty * 8];
            float4 a1 = *(const float4*)&As[k][ty * 8 + 4];
            float4 b0 = *(const float4*)&Bs[k][tx * 8];
            float4 b1 = *(const float4*)&Bs[k][tx * 8 + 4];
            float ar[8] = {a0.x, a0.y, a0.z, a0.w, a1.x, a1.y, a1.z, a1.w};
            float br[8] = {b0.x, b0.y, b0.z, b0.w, b1.x, b1.y, b1.z, b1.w};
#pragma unroll
            for (int i = 0; i < 8; ++i)
#pragma unroll
                for (int j = 0; j < 8; ++j)
                    acc[i][j] += ar[i] * br[j];
        }
        __syncthreads();
    }

    float brow[8];
    if (MODE >= 1) {
#pragma unroll
        for (int j = 0; j < 8; ++j) brow[j] = bias[n0 + tx * 8 + j];
    }
#pragma unroll
    for (int i = 0; i < 8; ++i) {
        long row = m0 + ty * 8 + i;
        float v[8];
#pragma unroll
        for (int j = 0; j < 8; ++j) {
            float x = acc[i][j];
            if (MODE >= 1) x += brow[j];
            if (MODE == 2) x = tanhf(x);
            v[j] = x;
        }
        float4* dst = (float4*)&Cb[row * ldc + n0 + tx * 8];
        dst[0] = make_float4(v[0], v[1], v[2], v[3]);
        dst[1] = make_float4(v[4], v[5], v[6], v[7]);
    }
}

__global__ __launch_bounds__(256) void softmax2048(float* __restrict__ S)
{
    __shared__ float red[4];
    float* p = S + (long)blockIdx.x * 2048 + threadIdx.x * 8;
    float4 a = ((float4*)p)[0];
    float4 b = ((float4*)p)[1];

    float m = fmaxf(fmaxf(fmaxf(a.x, a.y), fmaxf(a.z, a.w)),
                    fmaxf(fmaxf(b.x, b.y), fmaxf(b.z, b.w)));
#pragma unroll
    for (int off = 32; off; off >>= 1) m = fmaxf(m, __shfl_xor(m, off));
    int wid = threadIdx.x >> 6;
    if ((threadIdx.x & 63) == 0) red[wid] = m;
    __syncthreads();
    m = fmaxf(fmaxf(red[0], red[1]), fmaxf(red[2], red[3]));
    __syncthreads();

    a.x = __expf(a.x - m); a.y = __expf(a.y - m);
    a.z = __expf(a.z - m); a.w = __expf(a.w - m);
    b.x = __expf(b.x - m); b.y = __expf(b.y - m);
    b.z = __expf(b.z - m); b.w = __expf(b.w - m);

    float s = a.x + a.y + a.z + a.w + b.x + b.y + b.z + b.w;
#pragma unroll
    for (int off = 32; off; off >>= 1) s += __shfl_xor(s, off);
    if ((threadIdx.x & 63) == 0) red[wid] = s;
    __syncthreads();
    s = red[0] + red[1] + red[2] + red[3];
    float inv = 1.0f / s;

    a.x *= inv; a.y *= inv; a.z *= inv; a.w *= inv;
    b.x *= inv; b.y *= inv; b.z *= inv; b.w *= inv;
    ((float4*)p)[0] = a;
    ((float4*)p)[1] = b;
}

// ===========================================================================
extern "C" void kernel_launch(void* const* d_in, const int* in_sizes, int n_in,
                              void* d_out, int out_size, void* d_ws, size_t ws_size,
                              hipStream_t stream)
{
    const float* query  = (const float*)d_in[0];
    const float* values = (const float*)d_in[1];
    const float* W1     = (const float*)d_in[2];
    const float* b1     = (const float*)d_in[3];
    const float* W2     = (const float*)d_in[4];
    const float* b2     = (const float*)d_in[5];
    float* out = (float*)d_out;

    const int Bc = 32, QL = 512, SL = 2048, D = 1024, F = 2048;
    const long R = (long)QL * Bc;   // 16384

    char* p = (char*)d_ws;
    auto take = [&](size_t bytes) -> char* {
        char* r = p;
        p += (bytes + 255) & ~(size_t)255;
        return r;
    };

    ushort* q_hi  = (ushort*)take((size_t)R * D * 2);
    ushort* q_lo  = (ushort*)take((size_t)R * D * 2);
    ushort* w1_hi = (ushort*)take((size_t)D * D * 2);
    ushort* w1_lo = (ushort*)take((size_t)D * D * 2);
    ushort* w2_hi = (ushort*)take((size_t)D * F * 2);
    ushort* w2_lo = (ushort*)take((size_t)D * F * 2);
    ushort* qr_hi = (ushort*)take((size_t)R * D * 2);
    ushort* qr_lo = (ushort*)take((size_t)R * D * 2);
    ushort* at_hi = (ushort*)take((size_t)R * D * 2);
    size_t fixedBytes = (size_t)(p - (char*)d_ws);

    // per batch: vals hi+lo+vT (3 x 4 MB) + scores f32 (4 MB) + P bf16 (2 MB)
    const size_t perBatch = (size_t)SL * D * 2 * 3 + (size_t)QL * SL * 4 + (size_t)QL * SL * 2 + 2048;
    long availB = (long)ws_size - (long)fixedBytes;
    int g = availB > 0 ? (int)(availB / (long)perBatch) : 0;
    if (g > 32) g = 32;

    if (g >= 1) {
        // ----------------------- fast split-bf16 MFMA path -----------------
        ushort* vals_hi = (ushort*)take((size_t)SL * D * 2 * g);
        ushort* vals_lo = (ushort*)take((size_t)SL * D * 2 * g);
        ushort* vT      = (ushort*)take((size_t)SL * D * 2 * g);
        float*  scores  = (float*) take((size_t)QL * SL * 4 * g);
        ushort* P       = (ushort*)take((size_t)QL * SL * 2 * g);

        split_pair_k<<<2048, 256, 0, stream>>>(query, q_hi, q_lo, R * D / 4);
        split_pair_k<<<1024, 256, 0, stream>>>(W1, w1_hi, w1_lo, (long)D * D / 4);
        split_pair_k<<<1024, 256, 0, stream>>>(W2, w2_hi, w2_lo, (long)D * F / 4);

        // K1: qr = query.W1^T + b1  (3-term split segments) -> bf16 pair
        gemm8p<2><<<dim3(D / 256, R / 256, 1), 512, 0, stream>>>(
            q_hi, q_hi, q_lo, w1_hi, w1_lo, w1_hi,
            D, D, 16, 3, b1,
            nullptr, qr_hi, qr_lo,
            D, 0, 0, 0);

        for (int b0 = 0; b0 < Bc; b0 += g) {
            int gc = (Bc - b0 < g) ? (Bc - b0) : g;

            values_conv_k<<<dim3(SL / 64, D / 64, gc), 256, 0, stream>>>(
                values, vals_hi, vals_lo, vT, b0, gc);

            // K2: scores = qr . values  (3-term split segments) -> f32
            gemm8p<0><<<dim3(SL / 256, QL / 256, gc), 512, 0, stream>>>(
                qr_hi + (size_t)b0 * D, qr_hi + (size_t)b0 * D, qr_lo + (size_t)b0 * D,
                vals_hi, vals_lo, vals_hi,
                (long)Bc * D, (long)gc * D, 16, 3, nullptr,
                scores, nullptr, nullptr,
                SL, D, D, (long)QL * SL);

            softmax2048b_k<<<gc * QL, 256, 0, stream>>>(scores, P);

            // K4: att = P . vT  (1-term, K=2048) -> bf16 hi only
            gemm8p<2><<<dim3(D / 256, QL / 256, gc), 512, 0, stream>>>(
                P, P, P, vT, vT, vT,
                SL, SL, 32, 1, nullptr,
                nullptr, at_hi + (size_t)b0 * D, nullptr,
                (long)Bc * D, (long)QL * SL, (long)D * SL, D);
        }

        // K5: out = tanh([att | query] . W2^T + b2)  (1-term, 2 K-segments)
        gemm8p<3><<<dim3(D / 256, R / 256, 1), 512, 0, stream>>>(
            at_hi, q_hi, q_hi, w2_hi, w2_hi + 1024, w2_hi,
            D, F, 16, 2, b2,
            out, nullptr, nullptr,
            D, 0, 0, 0);
        return;
    }

    // ----------------------- fp32 fallback ---------------------------------
    float* qr = (float*)d_ws;
    size_t qrBytes = (size_t)R * D * sizeof(float);
    float* sc = (float*)((char*)d_ws + qrBytes);
    size_t scPerB = (size_t)QL * SL * sizeof(float);

    int grp = 32;
    if (ws_size < qrBytes + 32 * scPerB) {
        size_t avail = ws_size > qrBytes ? ws_size - qrBytes : 0;
        grp = (int)(avail / scPerB);
        if (grp < 1)  grp = 1;
        if (grp > 32) grp = 32;
    }

    {
        dim3 gd(D / BNF, R / BMF, 1);
        gemm_f32<true, 1><<<gd, 256, 0, stream>>>(
            query, nullptr, 1 << 30, W1, b1, qr,
            D, D, D, D, 0, 0, 0);
    }
    for (int b0 = 0; b0 < Bc; b0 += grp) {
        int gg = (Bc - b0 < grp) ? (Bc - b0) : grp;
        {
            dim3 gd(SL / BNF, QL / BMF, gg);
            gemm_f32<true, 0><<<gd, 256, 0, stream>>>(
                qr + (size_t)b0 * D, nullptr, 1 << 30,
                values + (size_t)b0 * D, nullptr, sc,
                (long)Bc * D, (long)Bc * D, SL, D,
                D, D, (long)QL * SL);
        }
        softmax2048<<<gg * QL, 256, 0, stream>>>(sc);
        {
            dim3 gd(D / BNF, QL / BMF, gg);
            gemm_f32<false, 0><<<gd, 256, 0, stream>>>(
                sc, nullptr, 1 << 30,
                values + (size_t)b0 * D, nullptr, qr + (size_t)b0 * D,
                SL, (long)Bc * D, (long)Bc * D, SL,
                (long)QL * SL, D, D);
        }
    }
    {
        dim3 gd(D / BNF, R / BMF, 1);
        gemm_f32<true, 2><<<gd, 256, 0, stream>>>(
            qr, query, D, W2, b2, out,
            D, 2048, D, 2048, 0, 0, 0);
    }
}

// Round 8
// 641.113 us; speedup vs baseline: 1.2827x; 1.0005x over previous
//
#include <hip/hip_runtime.h>
#include <hip/hip_bf16.h>

// GlobalAttention: Q_LEN=512, SRC_LEN=2048, B=32, D=1024, F=2048
// Round 8: m201-faithful phase skeleton on the round-7 geometry:
//   per phase: RD(ds_read this phase's frags) -> STAGE(one half of next tile)
//              -> barrier -> lgkmcnt(0) -> setprio(1) 16 MFMA setprio(0)
//              -> [vmcnt(4)] -> barrier
//   (reads issued in the prior epoch overlap other waves' MFMA clusters;
//    vmcnt sits AFTER the MFMA so load latency is absorbed by compute;
//    B0 held in registers across ph0->ph3: 4 fewer ds_reads/tile)
// Graduated arrival: half staged at phase p lands by phase p+3 (vmcnt(4)).
// Numerics identical to rounds 4-7 (absmax 0.0088).

typedef __attribute__((ext_vector_type(8))) short bf16x8;
typedef __attribute__((ext_vector_type(4))) float f32x4;

__device__ __forceinline__ ushort f2bf(float x) {
    unsigned u = __builtin_bit_cast(unsigned, x);
    u += 0x7FFFu + ((u >> 16) & 1u);
    return (ushort)(u >> 16);
}
__device__ __forceinline__ float bf2f(ushort h) {
    unsigned u = (unsigned)h << 16;
    return __builtin_bit_cast(float, u);
}
__device__ __forceinline__ void async16(const ushort* g, ushort* l) {
    __builtin_amdgcn_global_load_lds(
        (const __attribute__((address_space(1))) unsigned int*)g,
        (__attribute__((address_space(3))) unsigned int*)l, 16, 0, 0);
}

#define WAITVM(N) asm volatile("s_waitcnt vmcnt(" #N ")" ::: "memory")
#define SBAR()    __builtin_amdgcn_sched_barrier(0)
#define ENDBAR()  do { SBAR(); __builtin_amdgcn_s_barrier(); SBAR(); } while (0)
#define PREMM()   do { SBAR(); __builtin_amdgcn_s_barrier();                  \
                       asm volatile("s_waitcnt lgkmcnt(0)" ::: "memory");     \
                       SBAR(); __builtin_amdgcn_s_setprio(1); } while (0)
#define POSTMM()  __builtin_amdgcn_s_setprio(0)

// read A-quadrant QM (4 m-frags x 2 k-windows) into av
#define RD_A(QM)                                                              \
  _Pragma("unroll") for (int mi = 0; mi < 4; ++mi)                            \
  _Pragma("unroll") for (int w = 0; w < 2; ++w) {                             \
    const int row_ = (QM)*128 + wmg*64 + mi*16 + lr;                          \
    av[mi][w] = *(const bf16x8*)(bufc + row_*64 + (((w*4+lg)^(lr&7))*8));     \
  }
// read B-quadrant QN (2 n-frags x 2 k-windows) into DST
#define RD_B(QN, DST)                                                         \
  _Pragma("unroll") for (int nj = 0; nj < 2; ++nj)                            \
  _Pragma("unroll") for (int w = 0; w < 2; ++w) {                             \
    const int row_ = (QN)*128 + wnd*32 + nj*16 + lr;                          \
    DST[nj][w] = *(const bf16x8*)(bufc + 16384 + row_*64 + (((w*4+lg)^(lr&7))*8)); \
  }
#define MM(QM, QN, BSRC)                                                      \
  _Pragma("unroll") for (int w = 0; w < 2; ++w)                               \
  _Pragma("unroll") for (int mi = 0; mi < 4; ++mi)                            \
  _Pragma("unroll") for (int nj = 0; nj < 2; ++nj)                            \
    acc[(QM)*4+mi][(QN)*2+nj] = __builtin_amdgcn_mfma_f32_16x16x32_bf16(      \
        av[mi][w], BSRC[nj][w], acc[(QM)*4+mi][(QN)*2+nj], 0, 0, 0);

// ---------------------------------------------------------------------------
// gemm8p: C[m,n] = sum_{seg} sum_k A_s[m*lda+k]*B_s[n*ldb+k]  (NT, K-segments)
// 256x256 tile, BK=64, 512 thr (8 waves: wmg=wid>>2, wnd=wid&3).
// Quadrant (qm,qn): rows qm*128+wmg*64.., cols qn*128+wnd*32.. ; acc[8][4].
// LDS per buffer: A [256][64] at 0, B [256][64] at 16384 elems; 8-slot XOR
// swizzle c16^(row&7) pre-applied on the global stage source and on ds_read.
// OUTMODE: 0=f32, 2=bf16 hi (+lo if non-null)(+bias if non-null), 3=tanh(x+bias)
// ---------------------------------------------------------------------------
template<int OUTMODE>
__global__ __launch_bounds__(512, 2) void gemm8p(
    const ushort* __restrict__ A0s, const ushort* __restrict__ A1s, const ushort* __restrict__ A2s,
    const ushort* __restrict__ B0s, const ushort* __restrict__ B1s, const ushort* __restrict__ B2s,
    long lda, long ldb, int tps, int nseg,
    const float* __restrict__ bias,
    float* __restrict__ Cf, ushort* __restrict__ Chi, ushort* __restrict__ Clo,
    long ldc, long sAb, long sBb, long sCb)
{
    __shared__ ushort lds[2][32768];   // 2 x 64 KiB

    const int t   = threadIdx.x;
    const int l   = t & 63;
    const int wid = t >> 6;
    const int lr  = l & 15;
    const int lg  = l >> 4;
    const int wmg = wid >> 2;   // 0..1  (m position)
    const int wnd = wid & 3;    // 0..3  (n position)

    // XCD-aware bijective block swizzle (all grids have nwg % 8 == 0)
    const int gx = gridDim.x, gy = gridDim.y;
    const int nwg = gx * gy * gridDim.z;
    int w0 = ((int)blockIdx.z * gy + (int)blockIdx.y) * gx + (int)blockIdx.x;
    w0 = (w0 & 7) * (nwg >> 3) + (w0 >> 3);
    const int bx = w0 % gx;
    const int by = (w0 / gx) % gy;
    const int bz = w0 / (gx * gy);

    const long m0 = (long)by * 256;
    const long n0 = (long)bx * 256;

    const ushort* Asg[3] = { A0s + (long)bz * sAb, A1s + (long)bz * sAb, A2s + (long)bz * sAb };
    const ushort* Bsg[3] = { B0s + (long)bz * sBb, B1s + (long)bz * sBb, B2s + (long)bz * sBb };
    const int NTt = nseg * tps;

    // staging: half-tile = 128 rows x 64 k = 2 loads/thread; dest linear,
    // source slot pre-swizzled (t&7)^(rA&7) (row+64 preserves &7).
    const int  rA = t >> 3;
    const long cS = (long)((t & 7) ^ (rA & 7)) * 8;

    auto STAGE = [&](int kt1, bool isB, int half, int destoff) {
        int s2 = (kt1 >= tps) + (kt1 >= 2 * tps);
        long ko = (long)(kt1 - s2 * tps) * 64;
        const ushort* base = isB ? Bsg[s2] : Asg[s2];
        long ld = isB ? ldb : lda;
        long rb = isB ? n0 : m0;
        const ushort* src = base + (rb + half * 128 + rA) * ld + ko + cS;
        ushort* d = &lds[kt1 & 1][destoff + t * 8];
        async16(src, d);
        async16(src + 64 * ld, d + 4096);
    };

    const f32x4 zero = {0.f, 0.f, 0.f, 0.f};
    f32x4 acc[8][4];
#pragma unroll
    for (int i = 0; i < 8; ++i)
#pragma unroll
        for (int j = 0; j < 4; ++j) acc[i][j] = zero;

    // prologue: tile 0, stage order A0,B0,B1,A1; enter with A0,B0 landed
    STAGE(0, false, 0, 0);
    STAGE(0, true,  0, 16384);
    STAGE(0, true,  1, 24576);
    STAGE(0, false, 1, 8192);
    WAITVM(4);
    ENDBAR();

    bf16x8 av[4][2], bv[2][2], bv0[2][2];

    for (int kt = 0; kt < NTt - 1; ++kt) {
        const ushort* bufc = &lds[kt & 1][0];
        // ph0: quadrant (0,0); stage next A0; vm -> B1(kt) landed for ph1
        RD_A(0); RD_B(0, bv0);
        STAGE(kt + 1, false, 0, 0);
        PREMM(); MM(0, 0, bv0); POSTMM();
        WAITVM(4); ENDBAR();
        // ph1: quadrant (0,1); stage next B0; vm -> A1(kt) landed for ph2
        RD_B(1, bv);
        STAGE(kt + 1, true, 0, 16384);
        PREMM(); MM(0, 1, bv); POSTMM();
        WAITVM(4); ENDBAR();
        // ph2: quadrant (1,1); stage next B1; ph3 needs nothing new
        RD_A(1);
        STAGE(kt + 1, true, 1, 24576);
        PREMM(); MM(1, 1, bv); POSTMM();
        ENDBAR();
        // ph3: quadrant (1,0) reuses bv0; stage next A1; vm -> A0,B0(kt+1)
        STAGE(kt + 1, false, 1, 8192);
        PREMM(); MM(1, 0, bv0); POSTMM();
        WAITVM(4); ENDBAR();
    }
    {   // last tile: no staging; graduated drain
        const ushort* bufc = &lds[(NTt - 1) & 1][0];
        RD_A(0); RD_B(0, bv0);
        PREMM(); MM(0, 0, bv0); POSTMM();
        WAITVM(2); ENDBAR();
        RD_B(1, bv);
        PREMM(); MM(0, 1, bv); POSTMM();
        WAITVM(0); ENDBAR();
        RD_A(1);
        PREMM(); MM(1, 1, bv); POSTMM();
        ENDBAR();
        PREMM(); MM(1, 0, bv0); POSTMM();
    }

    // epilogue: 16x16 C/D mapping col = l&15, row = (l>>4)*4 + reg
    float*  Cfb = Cf  ? (Cf  + (long)bz * sCb) : nullptr;
    ushort* Chb = Chi ? (Chi + (long)bz * sCb) : nullptr;
    ushort* Clb = Clo ? (Clo + (long)bz * sCb) : nullptr;
#pragma unroll
    for (int qn = 0; qn < 2; ++qn)
#pragma unroll
    for (int nj = 0; nj < 2; ++nj) {
        long n = n0 + qn * 128 + wnd * 32 + nj * 16 + lr;
        float bvs = 0.f;
        if (OUTMODE == 3) bvs = bias[n];
        if (OUTMODE == 2) { if (bias) bvs = bias[n]; }
#pragma unroll
        for (int qm = 0; qm < 2; ++qm)
#pragma unroll
        for (int mi = 0; mi < 4; ++mi) {
            long mb = m0 + qm * 128 + wmg * 64 + mi * 16 + lg * 4;
#pragma unroll
            for (int r = 0; r < 4; ++r) {
                float x = acc[qm * 4 + mi][qn * 2 + nj][r] + bvs;
                long idx = (mb + r) * ldc + n;
                if (OUTMODE == 3) {
                    Cfb[idx] = tanhf(x);
                } else if (OUTMODE == 2) {
                    ushort h = f2bf(x);
                    Chb[idx] = h;
                    if (Clb) Clb[idx] = f2bf(x - bf2f(h));
                } else {
                    Cfb[idx] = x;
                }
            }
        }
    }
}

// ---------------------------------------------------------------------------
// Elementwise f32 -> (hi, lo) bf16 pair
// ---------------------------------------------------------------------------
__global__ __launch_bounds__(256) void split_pair_k(
    const float* __restrict__ in, ushort* __restrict__ hi, ushort* __restrict__ lo, long n4)
{
    long i = (long)blockIdx.x * 256 + threadIdx.x;
    const long stride = (long)gridDim.x * 256;
    for (; i < n4; i += stride) {
        float4 x = ((const float4*)in)[i];
        ushort4 h, lw;
        h.x = f2bf(x.x); lw.x = f2bf(x.x - bf2f(h.x));
        h.y = f2bf(x.y); lw.y = f2bf(x.y - bf2f(h.y));
        h.z = f2bf(x.z); lw.z = f2bf(x.z - bf2f(h.z));
        h.w = f2bf(x.w); lw.w = f2bf(x.w - bf2f(h.w));
        ((ushort4*)hi)[i] = h;
        ((ushort4*)lo)[i] = lw;
    }
}

// ---------------------------------------------------------------------------
// values [2048][32][1024] f32 -> per batch-group:
//   vhi/vlo [(s*gc+bi)][1024] bf16 pair  (K2 B-operand, NT)
//   vT [bi][1024][2048] bf16             (K4 B-operand, NT)
// ---------------------------------------------------------------------------
__global__ __launch_bounds__(256) void values_conv_k(
    const float* __restrict__ values,
    ushort* __restrict__ vhi, ushort* __restrict__ vlo, ushort* __restrict__ vT,
    int b0, int gc)
{
    __shared__ float tile[64][65];
    const int t  = threadIdx.x;
    const int s0 = blockIdx.x * 64;
    const int v0 = blockIdx.y * 64;
    const int bi = blockIdx.z;
    const int b  = b0 + bi;
#pragma unroll
    for (int i = 0; i < 4; ++i) {
        int c = t + i * 256;
        int r = c >> 4;
        int qq = c & 15;
        float4 x = *(const float4*)(values + ((long)(s0 + r) * 32 + b) * 1024 + v0 + qq * 4);
        ushort4 h, lw;
        h.x = f2bf(x.x); lw.x = f2bf(x.x - bf2f(h.x));
        h.y = f2bf(x.y); lw.y = f2bf(x.y - bf2f(h.y));
        h.z = f2bf(x.z); lw.z = f2bf(x.z - bf2f(h.z));
        h.w = f2bf(x.w); lw.w = f2bf(x.w - bf2f(h.w));
        long rowoff = ((long)(s0 + r) * gc + bi) * 1024 + v0 + qq * 4;
        *(ushort4*)(vhi + rowoff) = h;
        *(ushort4*)(vlo + rowoff) = lw;
        tile[r][qq * 4 + 0] = x.x;
        tile[r][qq * 4 + 1] = x.y;
        tile[r][qq * 4 + 2] = x.z;
        tile[r][qq * 4 + 3] = x.w;
    }
    __syncthreads();
    const int vr = t >> 2;
    const int ss = (t & 3) * 16;
    ushort* dst = vT + ((long)bi * 1024 + v0 + vr) * 2048 + s0 + ss;
#pragma unroll
    for (int j = 0; j < 4; ++j) {
        ushort4 o;
        o.x = f2bf(tile[ss + j * 4 + 0][vr]);
        o.y = f2bf(tile[ss + j * 4 + 1][vr]);
        o.z = f2bf(tile[ss + j * 4 + 2][vr]);
        o.w = f2bf(tile[ss + j * 4 + 3][vr]);
        *(ushort4*)(dst + j * 4) = o;
    }
}

// softmax over 2048-rows, f32 in -> bf16 P out. One 256-thread block per row.
__global__ __launch_bounds__(256) void softmax2048b_k(
    const float* __restrict__ S, ushort* __restrict__ P)
{
    __shared__ float red[4];
    const long row = blockIdx.x;
    const float* p = S + row * 2048 + threadIdx.x * 8;
    float4 a = ((const float4*)p)[0];
    float4 b = ((const float4*)p)[1];

    float m = fmaxf(fmaxf(fmaxf(a.x, a.y), fmaxf(a.z, a.w)),
                    fmaxf(fmaxf(b.x, b.y), fmaxf(b.z, b.w)));
#pragma unroll
    for (int off = 32; off; off >>= 1) m = fmaxf(m, __shfl_xor(m, off));
    int wid = threadIdx.x >> 6;
    if ((threadIdx.x & 63) == 0) red[wid] = m;
    __syncthreads();
    m = fmaxf(fmaxf(red[0], red[1]), fmaxf(red[2], red[3]));
    __syncthreads();

    a.x = __expf(a.x - m); a.y = __expf(a.y - m);
    a.z = __expf(a.z - m); a.w = __expf(a.w - m);
    b.x = __expf(b.x - m); b.y = __expf(b.y - m);
    b.z = __expf(b.z - m); b.w = __expf(b.w - m);

    float s = a.x + a.y + a.z + a.w + b.x + b.y + b.z + b.w;
#pragma unroll
    for (int off = 32; off; off >>= 1) s += __shfl_xor(s, off);
    if ((threadIdx.x & 63) == 0) red[wid] = s;
    __syncthreads();
    s = red[0] + red[1] + red[2] + red[3];
    float inv = 1.0f / s;

    ushort* qp = P + row * 2048 + threadIdx.x * 8;
    ushort4 oA, oB;
    oA.x = f2bf(a.x * inv); oA.y = f2bf(a.y * inv);
    oA.z = f2bf(a.z * inv); oA.w = f2bf(a.w * inv);
    oB.x = f2bf(b.x * inv); oB.y = f2bf(b.y * inv);
    oB.z = f2bf(b.z * inv); oB.w = f2bf(b.w * inv);
    ((ushort4*)qp)[0] = oA;
    ((ushort4*)qp)[1] = oB;
}

// ===========================================================================
// Fallback fp32 path (used only if ws_size is too small)
// ===========================================================================
#define BMF 128
#define BNF 128
#define BKF 16

template<bool NT, int MODE>
__global__ __launch_bounds__(256) void gemm_f32(
    const float* __restrict__ A, const float* __restrict__ A2, int Ksplit,
    const float* __restrict__ Bm, const float* __restrict__ bias,
    float* __restrict__ C,
    long lda, long ldb, long ldc, int K,
    long sAb, long sBb, long sCb)
{
    __shared__ float As[BKF][BMF + 4];
    __shared__ float Bs[BKF][BNF + 4];

    const int bz = blockIdx.z;
    const float* Ab  = A + (long)bz * sAb;
    const float* A2b = A2 ? (A2 + (long)bz * sAb) : nullptr;
    const float* Bb  = Bm + (long)bz * sBb;
    float*       Cb  = C + (long)bz * sCb;

    const int m0 = blockIdx.y * BMF;
    const int n0 = blockIdx.x * BNF;
    const int t  = threadIdx.x;
    const int tx = t & 15;
    const int ty = t >> 4;

    float acc[8][8];
#pragma unroll
    for (int i = 0; i < 8; ++i)
#pragma unroll
        for (int j = 0; j < 8; ++j) acc[i][j] = 0.f;

    for (int k0 = 0; k0 < K; k0 += BKF) {
        const float* Asrc = (A2b && k0 >= Ksplit) ? (A2b - Ksplit) : Ab;
#pragma unroll
        for (int c = 0; c < 2; ++c) {
            int chunk = t + c * 256;
            int row = chunk >> 2;
            int kq  = chunk & 3;
            float4 v = *(const float4*)(Asrc + (long)(m0 + row) * lda + k0 + kq * 4);
            As[kq * 4 + 0][row] = v.x;
            As[kq * 4 + 1][row] = v.y;
            As[kq * 4 + 2][row] = v.z;
            As[kq * 4 + 3][row] = v.w;
        }
        if (NT) {
#pragma unroll
            for (int c = 0; c < 2; ++c) {
                int chunk = t + c * 256;
                int row = chunk >> 2;
                int kq  = chunk & 3;
                float4 v = *(const float4*)(Bb + (long)(n0 + row) * ldb + k0 + kq * 4);
                Bs[kq * 4 + 0][row] = v.x;
                Bs[kq * 4 + 1][row] = v.y;
                Bs[kq * 4 + 2][row] = v.z;
                Bs[kq * 4 + 3][row] = v.w;
            }
        } else {
#pragma unroll
            for (int c = 0; c < 2; ++c) {
                int chunk = t + c * 256;
                int kr = chunk >> 5;
                int vq = chunk & 31;
                float4 v = *(const float4*)(Bb + (long)(k0 + kr) * ldb + n0 + vq * 4);
                *(float4*)&Bs[kr][vq * 4] = v;
            }
        }
        __syncthreads();

#pragma unroll
        for (int k = 0; k < BKF; ++k) {
            float4 a0 = *(const float4*)&As[k][ty * 8];
            float4 a1 = *(const float4*)&As[k][ty * 8 + 4];
            float4 b0 = *(const float4*)&Bs[k][tx * 8];
            float4 b1 = *(const float4*)&Bs[k][tx * 8 + 4];
            float ar[8] = {a0.x, a0.y, a0.z, a0.w, a1.x, a1.y, a1.z, a1.w};
            float br[8] = {b0.x, b0.y, b0.z, b0.w, b1.x, b1.y, b1.z, b1.w};
#pragma unroll
            for (int i = 0; i < 8; ++i)
#pragma unroll
                for (int j = 0; j < 8; ++j)
                    acc[i][j] += ar[i] * br[j];
        }
        __syncthreads();
    }

    float brow[8];
    if (MODE >= 1) {
#pragma unroll
        for (int j = 0; j < 8; ++j) brow[j] = bias[n0 + tx * 8 + j];
    }
#pragma unroll
    for (int i = 0; i < 8; ++i) {
        long row = m0 + ty * 8 + i;
        float v[8];
#pragma unroll
        for (int j = 0; j < 8; ++j) {
            float x = acc[i][j];
            if (MODE >= 1) x += brow[j];
            if (MODE == 2) x = tanhf(x);
            v[j] = x;
        }
        float4* dst = (float4*)&Cb[row * ldc + n0 + tx * 8];
        dst[0] = make_float4(v[0], v[1], v[2], v[3]);
        dst[1] = make_float4(v[4], v[5], v[6], v[7]);
    }
}

__global__ __launch_bounds__(256) void softmax2048(float* __restrict__ S)
{
    __shared__ float red[4];
    float* p = S + (long)blockIdx.x * 2048 + threadIdx.x * 8;
    float4 a = ((float4*)p)[0];
    float4 b = ((float4*)p)[1];

    float m = fmaxf(fmaxf(fmaxf(a.x, a.y), fmaxf(a.z, a.w)),
                    fmaxf(fmaxf(b.x, b.y), fmaxf(b.z, b.w)));
#pragma unroll
    for (int off = 32; off; off >>= 1) m = fmaxf(m, __shfl_xor(m, off));
    int wid = threadIdx.x >> 6;
    if ((threadIdx.x & 63) == 0) red[wid] = m;
    __syncthreads();
    m = fmaxf(fmaxf(red[0], red[1]), fmaxf(red[2], red[3]));
    __syncthreads();

    a.x = __expf(a.x - m); a.y = __expf(a.y - m);
    a.z = __expf(a.z - m); a.w = __expf(a.w - m);
    b.x = __expf(b.x - m); b.y = __expf(b.y - m);
    b.z = __expf(b.z - m); b.w = __expf(b.w - m);

    float s = a.x + a.y + a.z + a.w + b.x + b.y + b.z + b.w;
#pragma unroll
    for (int off = 32; off; off >>= 1) s += __shfl_xor(s, off);
    if ((threadIdx.x & 63) == 0) red[wid] = s;
    __syncthreads();
    s = red[0] + red[1] + red[2] + red[3];
    float inv = 1.0f / s;

    a.x *= inv; a.y *= inv; a.z *= inv; a.w *= inv;
    b.x *= inv; b.y *= inv; b.z *= inv; b.w *= inv;
    ((float4*)p)[0] = a;
    ((float4*)p)[1] = b;
}

// ===========================================================================
extern "C" void kernel_launch(void* const* d_in, const int* in_sizes, int n_in,
                              void* d_out, int out_size, void* d_ws, size_t ws_size,
                              hipStream_t stream)
{
    const float* query  = (const float*)d_in[0];
    const float* values = (const float*)d_in[1];
    const float* W1     = (const float*)d_in[2];
    const float* b1     = (const float*)d_in[3];
    const float* W2     = (const float*)d_in[4];
    const float* b2     = (const float*)d_in[5];
    float* out = (float*)d_out;

    const int Bc = 32, QL = 512, SL = 2048, D = 1024, F = 2048;
    const long R = (long)QL * Bc;   // 16384

    char* p = (char*)d_ws;
    auto take = [&](size_t bytes) -> char* {
        char* r = p;
        p += (bytes + 255) & ~(size_t)255;
        return r;
    };

    ushort* q_hi  = (ushort*)take((size_t)R * D * 2);
    ushort* q_lo  = (ushort*)take((size_t)R * D * 2);
    ushort* w1_hi = (ushort*)take((size_t)D * D * 2);
    ushort* w1_lo = (ushort*)take((size_t)D * D * 2);
    ushort* w2_hi = (ushort*)take((size_t)D * F * 2);
    ushort* w2_lo = (ushort*)take((size_t)D * F * 2);
    ushort* qr_hi = (ushort*)take((size_t)R * D * 2);
    ushort* qr_lo = (ushort*)take((size_t)R * D * 2);
    ushort* at_hi = (ushort*)take((size_t)R * D * 2);
    size_t fixedBytes = (size_t)(p - (char*)d_ws);

    // per batch: vals hi+lo+vT (3 x 4 MB) + scores f32 (4 MB) + P bf16 (2 MB)
    const size_t perBatch = (size_t)SL * D * 2 * 3 + (size_t)QL * SL * 4 + (size_t)QL * SL * 2 + 2048;
    long availB = (long)ws_size - (long)fixedBytes;
    int g = availB > 0 ? (int)(availB / (long)perBatch) : 0;
    if (g > 32) g = 32;

    if (g >= 1) {
        // ----------------------- fast split-bf16 MFMA path -----------------
        ushort* vals_hi = (ushort*)take((size_t)SL * D * 2 * g);
        ushort* vals_lo = (ushort*)take((size_t)SL * D * 2 * g);
        ushort* vT      = (ushort*)take((size_t)SL * D * 2 * g);
        float*  scores  = (float*) take((size_t)QL * SL * 4 * g);
        ushort* P       = (ushort*)take((size_t)QL * SL * 2 * g);

        split_pair_k<<<2048, 256, 0, stream>>>(query, q_hi, q_lo, R * D / 4);
        split_pair_k<<<1024, 256, 0, stream>>>(W1, w1_hi, w1_lo, (long)D * D / 4);
        split_pair_k<<<1024, 256, 0, stream>>>(W2, w2_hi, w2_lo, (long)D * F / 4);

        // K1: qr = query.W1^T + b1  (3-term split segments) -> bf16 pair
        gemm8p<2><<<dim3(D / 256, R / 256, 1), 512, 0, stream>>>(
            q_hi, q_hi, q_lo, w1_hi, w1_lo, w1_hi,
            D, D, 16, 3, b1,
            nullptr, qr_hi, qr_lo,
            D, 0, 0, 0);

        for (int b0 = 0; b0 < Bc; b0 += g) {
            int gc = (Bc - b0 < g) ? (Bc - b0) : g;

            values_conv_k<<<dim3(SL / 64, D / 64, gc), 256, 0, stream>>>(
                values, vals_hi, vals_lo, vT, b0, gc);

            // K2: scores = qr . values  (3-term split segments) -> f32
            gemm8p<0><<<dim3(SL / 256, QL / 256, gc), 512, 0, stream>>>(
                qr_hi + (size_t)b0 * D, qr_hi + (size_t)b0 * D, qr_lo + (size_t)b0 * D,
                vals_hi, vals_lo, vals_hi,
                (long)Bc * D, (long)gc * D, 16, 3, nullptr,
                scores, nullptr, nullptr,
                SL, D, D, (long)QL * SL);

            softmax2048b_k<<<gc * QL, 256, 0, stream>>>(scores, P);

            // K4: att = P . vT  (1-term, K=2048) -> bf16 hi only
            gemm8p<2><<<dim3(D / 256, QL / 256, gc), 512, 0, stream>>>(
                P, P, P, vT, vT, vT,
                SL, SL, 32, 1, nullptr,
                nullptr, at_hi + (size_t)b0 * D, nullptr,
                (long)Bc * D, (long)QL * SL, (long)D * SL, D);
        }

        // K5: out = tanh([att | query] . W2^T + b2)  (1-term, 2 K-segments)
        gemm8p<3><<<dim3(D / 256, R / 256, 1), 512, 0, stream>>>(
            at_hi, q_hi, q_hi, w2_hi, w2_hi + 1024, w2_hi,
            D, F, 16, 2, b2,
            out, nullptr, nullptr,
            D, 0, 0, 0);
        return;
    }

    // ----------------------- fp32 fallback ---------------------------------
    float* qr = (float*)d_ws;
    size_t qrBytes = (size_t)R * D * sizeof(float);
    float* sc = (float*)((char*)d_ws + qrBytes);
    size_t scPerB = (size_t)QL * SL * sizeof(float);

    int grp = 32;
    if (ws_size < qrBytes + 32 * scPerB) {
        size_t avail = ws_size > qrBytes ? ws_size - qrBytes : 0;
        grp = (int)(avail / scPerB);
        if (grp < 1)  grp = 1;
        if (grp > 32) grp = 32;
    }

    {
        dim3 gd(D / BNF, R / BMF, 1);
        gemm_f32<true, 1><<<gd, 256, 0, stream>>>(
            query, nullptr, 1 << 30, W1, b1, qr,
            D, D, D, D, 0, 0, 0);
    }
    for (int b0 = 0; b0 < Bc; b0 += grp) {
        int gg = (Bc - b0 < grp) ? (Bc - b0) : grp;
        {
            dim3 gd(SL / BNF, QL / BMF, gg);
            gemm_f32<true, 0><<<gd, 256, 0, stream>>>(
                qr + (size_t)b0 * D, nullptr, 1 << 30,
                values + (size_t)b0 * D, nullptr, sc,
                (long)Bc * D, (long)Bc * D, SL, D,
                D, D, (long)QL * SL);
        }
        softmax2048<<<gg * QL, 256, 0, stream>>>(sc);
        {
            dim3 gd(D / BNF, QL / BMF, gg);
            gemm_f32<false, 0><<<gd, 256, 0, stream>>>(
                sc, nullptr, 1 << 30,
                values + (size_t)b0 * D, nullptr, qr + (size_t)b0 * D,
                SL, (long)Bc * D, (long)Bc * D, SL,
                (long)QL * SL, D, D);
        }
    }
    {
        dim3 gd(D / BNF, R / BMF, 1);
        gemm_f32<true, 2><<<gd, 256, 0, stream>>>(
            qr, query, D, W2, b2, out,
            D, 2048, D, 2048, 0, 0, 0);
    }
}